// Round 7
// baseline (210.568 us; speedup 1.0000x reference)
//
#include <hip/hip_runtime.h>
#include <hip/hip_fp16.h>

#define Bsz 1024
#define Mm  2048
#define Rr  8192
#define EMAX 32   // ushort slots per E column (col nnz mean ~4.1)
#define SMAX 64   // ushort slots per S row    (row nnz mean ~16.4)

typedef unsigned short ushort_t;

// ---- pass 0: zero ecnt only (32 KB). ----
__global__ __launch_bounds__(256) void zero_ecnt(int* __restrict__ p) {
    p[blockIdx.x * 256 + threadIdx.x] = 0;       // grid 32 -> 8192
}

// ---- pass 1 (R1's exact measured form, 53.5us): blocks 0..511 transpose+log;
// 512..2559 S-scan; 2560..4607 E-scan. All three roles overlap in one dispatch.
// (R6 lesson: cooperative launch does not execute under the harness's graph
// capture -> device-wide sync ONLY via dispatch boundaries.)
__global__ __launch_bounds__(256) void prep_kernel(
    const float* __restrict__ conc, const int* __restrict__ E, const int* __restrict__ S,
    __half2* __restrict__ logcTh2, int* __restrict__ ecnt, ushort_t* __restrict__ elist,
    int* __restrict__ scnt, ushort_t* __restrict__ slist)
{
    __shared__ float tile[64][65];               // transpose role (16.6 KB)
    __shared__ int n_hits;                       // scan roles
    __shared__ int buf[256];
    const int bid = blockIdx.x;
    const int t   = threadIdx.x;

    if (bid < 512) {                             // ---- transpose + log -> fp16 ----
        const int mt = (bid & 31) * 64;          // Mm/64 = 32
        const int bt = (bid >> 5) * 64;
        const int lm = t & 63;
        const int w  = t >> 6;
        for (int i = w; i < 64; i += 4)
            tile[lm][i] = __logf(conc[(size_t)(bt + i) * Mm + mt + lm]);
        __syncthreads();
        const int s       = bt >> 7;             // b-slice (128 b)
        const int colbase = (bt & 127) >> 1;
        __half2* dst = logcTh2 + (size_t)s * (Mm * 64);
        for (int idx = t; idx < 64 * 32; idx += 256) {
            const int j = idx >> 5, bp = idx & 31;
            dst[(mt + j) * 64 + colbase + bp] =
                __floats2half2_rn(tile[j][2 * bp], tile[j][2 * bp + 1]);
        }
    } else if (bid < 2560) {                     // ---- S-scan: owns row m ----
        const int m = bid - 512;
        if (t == 0) n_hits = 0;
        __syncthreads();
        const int4* S4 = (const int4*)S + (size_t)m * 2048;
        int4 sv[8];
        #pragma unroll
        for (int u = 0; u < 8; ++u) sv[u] = S4[t + 256 * u];
        #pragma unroll
        for (int u = 0; u < 8; ++u) {
            const int r0 = (t + 256 * u) << 2;
            int v[4] = {sv[u].x, sv[u].y, sv[u].z, sv[u].w};
            #pragma unroll
            for (int q = 0; q < 4; ++q)
                if (v[q]) {
                    int i = atomicAdd(&n_hits, 1);          // LDS atomic
                    if (i < 256) buf[i] = ((v[q] + 2) << 13) | (r0 + q);
                }
        }
        __syncthreads();
        const int sn = min(n_hits, SMAX);
        if (t == 0) scnt[m] = sn;
        if (t < SMAX)                            // write ALL slots: pads are safe
            slist[m * SMAX + t] = (t < sn) ? (ushort_t)buf[t]
                                           : (ushort_t)0x4000;   // enc 2 -> s=0
    } else {                                     // ---- E-scan: owns row m ----
        const int m = bid - 2560;
        if (t == 0) n_hits = 0;
        __syncthreads();
        const int4* E4 = (const int4*)E + (size_t)m * 2048;
        int4 ev[8];
        #pragma unroll
        for (int u = 0; u < 8; ++u) ev[u] = E4[t + 256 * u];
        #pragma unroll
        for (int u = 0; u < 8; ++u) {
            const int r0 = (t + 256 * u) << 2;
            int v[4] = {ev[u].x, ev[u].y, ev[u].z, ev[u].w};
            #pragma unroll
            for (int q = 0; q < 4; ++q)
                if (v[q]) {
                    int i = atomicAdd(&n_hits, 1);          // LDS atomic
                    if (i < 256) buf[i] = (v[q] << 13) | (r0 + q);
                }
        }
        __syncthreads();
        const int en = min(n_hits, 256);
        if (t < en) {
            int wv = buf[t];
            int r  = wv & 0x1FFF;
            int e  = wv >> 13;
            int slot = atomicAdd(&ecnt[r], 1);              // ~16 atomics/block
            if (slot < EMAX) elist[r * EMAX + slot] = (ushort_t)((e << 11) | m);
        }
    }
}

// ---- fused rates+assemble: out[b][m] = sum_r s_mr * k_r * exp(sum e*logc) ----
// v recomputed on demand per slist word (wave-uniform r): kills the 16MB VTh
// write + 16MB read and one whole dispatch. ~4.1x r-eval recompute, but all
// gathers hit the XCD-pinned 512KB lc slice (L2), and v stays fp32 (no fp16
// VTh rounding -> absmax should tighten). Metadata (ecnt/elist/kvec) batched
// 8-wide per slist int4 so the 3 latency hops (slist->elist->lc) pipeline.
#define EG2(word, c0, c1, A)                                                   \
    w = (unsigned)(word);                                                      \
    v0 = (c0) ? (float)((w & 0xFFFF) >> 11) : 0.f;                             \
    v1 = (c1) ? (float)(w >> 27) : 0.f;                                        \
    g = __half22float2(lc[(w & 0x7FF) * 64 + col]);                            \
    A.x += v0 * g.x;  A.y += v0 * g.y;                                         \
    g = __half22float2(lc[((w >> 16) & 0x7FF) * 64 + col]);                    \
    A.x += v1 * g.x;  A.y += v1 * g.y;

__device__ __forceinline__ void acc8(
    const int4 W, const __half2* __restrict__ lc, const float* __restrict__ kvec,
    const int* __restrict__ ecnt, const ushort_t* __restrict__ elist,
    const int col, float2& a)
{
    unsigned pw[4] = {(unsigned)W.x, (unsigned)W.y, (unsigned)W.z, (unsigned)W.w};
    int rr[8]; float sww[8]; int cc[8]; int2 LL[8]; float kk[8];
    #pragma unroll
    for (int q = 0; q < 8; ++q) {                // decode 8 slist words
        const unsigned w16 = (pw[q >> 1] >> ((q & 1) * 16)) & 0xFFFFu;
        rr[q]  = (int)(w16 & 0x1FFF);
        sww[q] = (float)((int)(w16 >> 13) - 2);  // pads (0x4000) -> 0
    }
    #pragma unroll
    for (int q = 0; q < 8; ++q) {                // 24 independent meta loads
        cc[q] = min(ecnt[rr[q]], EMAX);
        LL[q] = *(const int2*)(elist + (rr[q] << 5));
        kk[q] = kvec[rr[q]];
    }
    unsigned w; float2 g; float v0, v1;
    #pragma unroll
    for (int q = 0; q < 8; ++q) {                // 32 independent lc gathers
        float2 acc2 = make_float2(0.f, 0.f);
        EG2(LL[q].x, cc[q] > 0, cc[q] > 1, acc2)
        EG2(LL[q].y, cc[q] > 2, cc[q] > 3, acc2)
        for (int j = 4; j < cc[q]; j += 4) {     // rare wave-uniform tails
            int2 T = *(const int2*)(elist + (rr[q] << 5) + j);
            EG2(T.x, j + 0 < cc[q], j + 1 < cc[q], acc2)
            EG2(T.y, j + 2 < cc[q], j + 3 < cc[q], acc2)
        }
        a.x += sww[q] * kk[q] * __expf(acc2.x);
        a.y += sww[q] * kk[q] * __expf(acc2.y);
    }
}

__global__ __launch_bounds__(256) void ra_kernel(
    const __half2* __restrict__ logcTh2, const float* __restrict__ kvec,
    const int* __restrict__ ecnt, const ushort_t* __restrict__ elist,
    const int* __restrict__ scnt, const ushort_t* __restrict__ slist,
    float* __restrict__ out)
{
    __shared__ float tile[128][9];               // [b-local][m-local] 4.6 KB
    const int s   = blockIdx.x & 7;              // XCD pin: lc slice 512 KB L2-hot
    const int mch = blockIdx.x >> 3;             // 0..255, 8 m each
    const int col = threadIdx.x & 63;
    const int wm  = __builtin_amdgcn_readfirstlane(threadIdx.x >> 6);
    const __half2* lc = logcTh2 + (size_t)s * (Mm * 64);
    const int m0 = mch * 8;

    #pragma unroll
    for (int i = 0; i < 2; ++i) {                // 2 rows per thread
        const int m  = m0 + i * 4 + wm;
        const int sn = min(scnt[m], SMAX);
        const int4* SL = (const int4*)(slist + (m << 6));   // 8 words / int4
        float2 a = make_float2(0.f, 0.f);
        acc8(SL[0], lc, kvec, ecnt, elist, col, a);
        acc8(SL[1], lc, kvec, ecnt, elist, col, a);
        for (int j = 16; j < sn; j += 8)         // pads materialized -> safe
            acc8(SL[j >> 3], lc, kvec, ecnt, elist, col, a);
        const int ml = i * 4 + wm;
        tile[2 * col][ml]     = a.x;             // b rows 2*col, 2*col+1
        tile[2 * col + 1][ml] = a.y;
    }
    __syncthreads();
    const int bl = threadIdx.x >> 1;             // 0..127
    const int fl = threadIdx.x & 1;              // 2 x float4 per b row
    float4 vv = *(const float4*)&tile[bl][fl * 4];
    *(float4*)(out + (size_t)(s * 128 + bl) * Mm + m0 + fl * 4) = vv;
}

extern "C" void kernel_launch(void* const* d_in, const int* in_sizes, int n_in,
                              void* d_out, int out_size, void* d_ws, size_t ws_size,
                              hipStream_t stream) {
    const float* conc = (const float*)d_in[0];
    const int*   E    = (const int*)d_in[1];
    const int*   S    = (const int*)d_in[2];
    const float* kvec = (const float*)d_in[3];
    float* out = (float*)d_out;

    // ws: logcTh fp16 (4 MB) | ecnt | scnt | elist u16 | slist u16  (VTh gone)
    __half2* logcTh2 = (__half2*)d_ws;
    int*    ecnt     = (int*)((char*)logcTh2 + (size_t)Mm * Bsz * sizeof(__half));
    int*    scnt     = ecnt + Rr;
    ushort_t* elist  = (ushort_t*)(scnt + Mm);
    ushort_t* slist  = elist + Rr * EMAX;
    const size_t need = (size_t)Mm * Bsz * sizeof(__half)
                      + (size_t)(Rr + Mm) * sizeof(int)
                      + (size_t)(Rr * EMAX + Mm * SMAX) * sizeof(ushort_t);
    if (ws_size < need) return;

    zero_ecnt<<<32, 256, 0, stream>>>(ecnt);
    prep_kernel<<<4608, 256, 0, stream>>>(conc, E, S, logcTh2, ecnt, elist, scnt, slist);
    ra_kernel<<<2048, 256, 0, stream>>>(logcTh2, kvec, ecnt, elist, scnt, slist, out);
}

// Round 8
// 175.548 us; speedup vs baseline: 1.1995x; 1.1995x over previous
//
#include <hip/hip_runtime.h>
#include <hip/hip_fp16.h>

#define Bsz 1024
#define Mm  2048
#define Rr  8192
#define EMAX 32   // ushort slots per E column (col nnz mean ~4.1)
#define SMAX 64   // ushort slots per S row    (row nnz mean ~16.4)

typedef unsigned short ushort_t;

// ---- pass 0: zero ecnt only (32 KB). ----
__global__ __launch_bounds__(256) void zero_ecnt(int* __restrict__ p) {
    p[blockIdx.x * 256 + threadIdx.x] = 0;       // grid 32 -> 8192
}

// ---- pass 1: blocks 0..511 transpose+log; 512..2559 E-scan (R5 form). ----
__global__ __launch_bounds__(256) void prep_kernel(
    const float* __restrict__ conc, const int* __restrict__ E,
    __half2* __restrict__ logcTh2, int* __restrict__ ecnt, ushort_t* __restrict__ elist)
{
    __shared__ int smem[64 * 65 + 1];            // transpose tile / escan buf+ctr
    const int bid = blockIdx.x;
    const int t   = threadIdx.x;

    if (bid < 512) {                             // ---- transpose + log -> fp16 ----
        float (*tile)[65] = (float(*)[65])smem;
        const int mt = (bid & 31) * 64;          // Mm/64 = 32
        const int bt = (bid >> 5) * 64;
        const int lm = t & 63;
        const int w  = t >> 6;
        for (int i = w; i < 64; i += 4)
            tile[lm][i] = __logf(conc[(size_t)(bt + i) * Mm + mt + lm]);
        __syncthreads();
        const int s       = bt >> 7;             // b-slice (128 b)
        const int colbase = (bt & 127) >> 1;
        __half2* dst = logcTh2 + (size_t)s * (Mm * 64);
        for (int idx = t; idx < 64 * 32; idx += 256) {
            const int j = idx >> 5, bp = idx & 31;
            dst[(mt + j) * 64 + colbase + bp] =
                __floats2half2_rn(tile[j][2 * bp], tile[j][2 * bp + 1]);
        }
    } else {                                     // ---- E-scan: owns row m ----
        const int m = bid - 512;
        int* buf = smem;
        int* nh  = smem + 256;
        if (t == 0) *nh = 0;
        __syncthreads();
        const int4* E4 = (const int4*)E + (size_t)m * 2048;
        int4 ev[8];
        #pragma unroll
        for (int u = 0; u < 8; ++u) ev[u] = E4[t + 256 * u];
        #pragma unroll
        for (int u = 0; u < 8; ++u) {
            const int r0 = (t + 256 * u) << 2;
            int v[4] = {ev[u].x, ev[u].y, ev[u].z, ev[u].w};
            #pragma unroll
            for (int q = 0; q < 4; ++q)
                if (v[q]) {
                    int i = atomicAdd(nh, 1);               // LDS atomic
                    if (i < 256) buf[i] = (v[q] << 13) | (r0 + q);
                }
        }
        __syncthreads();
        const int en = min(*nh, 256);
        if (t < en) {
            int wv = buf[t];
            int r  = wv & 0x1FFF;
            int e  = wv >> 13;
            int slot = atomicAdd(&ecnt[r], 1);              // ~16 atomics/block
            if (slot < EMAX) elist[r * EMAX + slot] = (ushort_t)((e << 11) | m);
        }
    }
}

// ---- pass 2 (fused, R5 form): alternating groups of 8 blocks: S-scan | rates.
// rates gather phase rewritten per R7 ra counters (VGPR=32, VALUBusy 42%,
// hbm 4% -> loads serialized in 2-4 reg runs): decode-all / load-all / math-all
// in 16-deep register batches so 16 L2 gathers are in flight per wave.
__global__ __launch_bounds__(256) void rs_kernel(
    const __half2* __restrict__ logcTh2, const float* __restrict__ kvec,
    const int* __restrict__ ecnt, const ushort_t* __restrict__ elist,
    const int* __restrict__ S, int* __restrict__ scnt, ushort_t* __restrict__ slist,
    __half2* __restrict__ VTh)
{
    __shared__ int smem[257];                    // S-scan buf+ctr (1 KB)
    const int bid   = blockIdx.x;
    const int t     = threadIdx.x;
    const int grp   = bid >> 3;
    const int lane8 = bid & 7;

    if ((grp & 1) == 0) {                        // ---- S-scan: owns row m ----
        const int m = (grp >> 1) * 8 + lane8;    // even grps -> m in [0,2048)
        int* buf = smem;
        int* nh  = smem + 256;
        if (t == 0) *nh = 0;
        __syncthreads();
        const int4* S4 = (const int4*)S + (size_t)m * 2048;
        int4 sv[8];
        #pragma unroll
        for (int u = 0; u < 8; ++u) sv[u] = S4[t + 256 * u];
        #pragma unroll
        for (int u = 0; u < 8; ++u) {
            const int r0 = (t + 256 * u) << 2;
            int v[4] = {sv[u].x, sv[u].y, sv[u].z, sv[u].w};
            #pragma unroll
            for (int q = 0; q < 4; ++q)
                if (v[q]) {
                    int i = atomicAdd(nh, 1);               // LDS atomic
                    if (i < 256) buf[i] = ((v[q] + 2) << 13) | (r0 + q);
                }
        }
        __syncthreads();
        const int sn = min(*nh, SMAX);
        if (t == 0) scnt[m] = sn;
        if (t < SMAX)                            // write ALL slots: pads are safe
            slist[m * SMAX + t] = (t < sn) ? (ushort_t)buf[t]
                                           : (ushort_t)0x4000;   // enc 2 -> s=0
        return;
    }
    // ---- rates: VTh[s][r][64] = k[r]*exp(sum e*logcTh[s][m][64]) ----
    const int s   = lane8;                       // == blockIdx&7: XCD pin
    const int rch = grp >> 1;                    // odd grps -> 0..255, 32 r each
    const int col = t & 63;
    const int wr  = __builtin_amdgcn_readfirstlane(t >> 6);
    const __half2* lc = logcTh2 + (size_t)s * (Mm * 64);
    __half2* vt = VTh + (size_t)s * (Rr * 64);
    const int rb = rch * 32 + wr * 8;

    int  cnt[8]; int2 L0[8]; float kk[8];        // batch phase: independent s_loads
    #pragma unroll
    for (int i = 0; i < 8; ++i) {
        const int r = rb + i;
        cnt[i] = min(ecnt[r], EMAX);             // clamp: atomic counts can exceed slots
        L0[i]  = *(const int2*)(elist + (r << 5));
        kk[i]  = kvec[r];
    }
    float2 acc[8];
    #pragma unroll
    for (int h = 0; h < 2; ++h) {                // 2 x 16-deep gather batches
        int ad[16]; float wg[16];
        #pragma unroll
        for (int i = 0; i < 4; ++i) {            // decode-all (4 r x 4 entries)
            const int ii = h * 4 + i;
            const unsigned wx = (unsigned)L0[ii].x, wy = (unsigned)L0[ii].y;
            ad[4 * i + 0] = (int)(wx & 0x7FFu) * 64 + col;
            ad[4 * i + 1] = (int)((wx >> 16) & 0x7FFu) * 64 + col;
            ad[4 * i + 2] = (int)(wy & 0x7FFu) * 64 + col;
            ad[4 * i + 3] = (int)((wy >> 16) & 0x7FFu) * 64 + col;
            wg[4 * i + 0] = (cnt[ii] > 0) ? (float)((wx & 0xFFFFu) >> 11) : 0.f;
            wg[4 * i + 1] = (cnt[ii] > 1) ? (float)(wx >> 27) : 0.f;
            wg[4 * i + 2] = (cnt[ii] > 2) ? (float)((wy & 0xFFFFu) >> 11) : 0.f;
            wg[4 * i + 3] = (cnt[ii] > 3) ? (float)(wy >> 27) : 0.f;
        }
        __half2 gv[16];
        #pragma unroll
        for (int j = 0; j < 16; ++j) gv[j] = lc[ad[j]];     // load-all: 16 in flight
        #pragma unroll
        for (int i = 0; i < 4; ++i) {            // math-all
            const int ii = h * 4 + i;
            float2 a = make_float2(0.f, 0.f);
            #pragma unroll
            for (int q = 0; q < 4; ++q) {
                const float2 gg = __half22float2(gv[4 * i + q]);
                a.x += wg[4 * i + q] * gg.x;
                a.y += wg[4 * i + q] * gg.y;
            }
            acc[ii] = a;
        }
    }
    {   // rare wave-uniform tails (cnt > 4)
        unsigned w; float2 g; float v0, v1;
        #define EG2(word, c0, c1, A)                                           \
            w = (unsigned)(word);                                              \
            v0 = (c0) ? (float)((w & 0xFFFF) >> 11) : 0.f;                     \
            v1 = (c1) ? (float)(w >> 27) : 0.f;                                \
            g = __half22float2(lc[(w & 0x7FF) * 64 + col]);                    \
            A.x += v0 * g.x;  A.y += v0 * g.y;                                 \
            g = __half22float2(lc[((w >> 16) & 0x7FF) * 64 + col]);            \
            A.x += v1 * g.x;  A.y += v1 * g.y;
        #pragma unroll
        for (int i = 0; i < 8; ++i) {
            for (int j = 4; j < cnt[i]; j += 4) {
                int2 T = *(const int2*)(elist + ((rb + i) << 5) + j);
                EG2(T.x, j + 0 < cnt[i], j + 1 < cnt[i], acc[i])
                EG2(T.y, j + 2 < cnt[i], j + 3 < cnt[i], acc[i])
            }
        }
        #undef EG2
    }
    #pragma unroll
    for (int i = 0; i < 8; ++i)
        vt[(rb + i) * 64 + col] =
            __floats2half2_rn(kk[i] * __expf(acc[i].x), kk[i] * __expf(acc[i].y));
}

// ---- pass 3: out[b][m] = sum s*VTh[s][r][64]; 16-deep gather batches. ----
__global__ __launch_bounds__(256) void assemble_kernel(
    const __half2* __restrict__ VTh, const int* __restrict__ scnt,
    const ushort_t* __restrict__ slist, float* __restrict__ out)
{
    __shared__ float tile[128][17];              // [b-local][m-local] 8.5 KB
    const int s   = blockIdx.x & 7;              // same XCD pin as rates
    const int mch = blockIdx.x >> 3;             // 0..127, 16 m each
    const int col = threadIdx.x & 63;
    const int wm  = __builtin_amdgcn_readfirstlane(threadIdx.x >> 6);
    const __half2* vt = VTh + (size_t)s * (Rr * 64);
    const int m0 = mch * 16;

    int scn[4]; int4 W0[4], W1[4];               // batch phase: independent s_loads
    #pragma unroll
    for (int i = 0; i < 4; ++i) {
        const int m = m0 + i * 4 + wm;
        scn[i] = min(scnt[m], SMAX);
        W0[i]  = *(const int4*)(slist + (m << 6));
        W1[i]  = *(const int4*)(slist + (m << 6) + 8);
    }
    #pragma unroll
    for (int i = 0; i < 4; ++i) {
        const int ml = i * 4 + wm;
        // decode-all: 16 entries from W0[i],W1[i]
        const unsigned wd[8] = {(unsigned)W0[i].x, (unsigned)W0[i].y,
                                (unsigned)W0[i].z, (unsigned)W0[i].w,
                                (unsigned)W1[i].x, (unsigned)W1[i].y,
                                (unsigned)W1[i].z, (unsigned)W1[i].w};
        int ad[16]; float swt[16];
        #pragma unroll
        for (int q = 0; q < 8; ++q) {
            const unsigned lo = wd[q] & 0xFFFFu, hi = wd[q] >> 16;
            ad[2 * q + 0]  = (int)(lo & 0x1FFFu) * 64 + col;
            ad[2 * q + 1]  = (int)(hi & 0x1FFFu) * 64 + col;
            swt[2 * q + 0] = (float)((int)(lo >> 13) - 2);   // pads -> 0
            swt[2 * q + 1] = (float)((int)(hi >> 13) - 2);
        }
        __half2 gv[16];
        #pragma unroll
        for (int q = 0; q < 16; ++q) gv[q] = vt[ad[q]];     // load-all: 16 in flight
        float2 a = make_float2(0.f, 0.f);
        #pragma unroll
        for (int q = 0; q < 16; ++q) {           // math-all
            const float2 gg = __half22float2(gv[q]);
            a.x += swt[q] * gg.x;
            a.y += swt[q] * gg.y;
        }
        {   // rare tails (sn > 16); pads materialized -> safe groups
            unsigned w; float2 v; float sw;
            #define SG(word, A)                                                \
                w = (unsigned)(word);                                          \
                v = __half22float2(vt[(w & 0x1FFF) * 64 + col]);               \
                sw = (float)((int)((w & 0xFFFF) >> 13) - 2);                   \
                A.x += sw * v.x;  A.y += sw * v.y;                             \
                v = __half22float2(vt[((w >> 16) & 0x1FFF) * 64 + col]);       \
                sw = (float)((int)(w >> 29) - 2);                              \
                A.x += sw * v.x;  A.y += sw * v.y;
            for (int j = 16; j < scn[i]; j += 8) {
                int4 T = *(const int4*)(slist + ((m0 + ml) << 6) + j);
                SG(T.x, a) SG(T.y, a) SG(T.z, a) SG(T.w, a)
            }
            #undef SG
        }
        tile[2 * col][ml]     = a.x;
        tile[2 * col + 1][ml] = a.y;
    }
    __syncthreads();
    #pragma unroll
    for (int pass = 0; pass < 2; ++pass) {
        const int bl = (threadIdx.x >> 2) + pass * 64;
        const int fl = threadIdx.x & 3;
        float4 vv = *(const float4*)&tile[bl][fl * 4];
        *(float4*)(out + (size_t)(s * 128 + bl) * Mm + m0 + fl * 4) = vv;
    }
}

extern "C" void kernel_launch(void* const* d_in, const int* in_sizes, int n_in,
                              void* d_out, int out_size, void* d_ws, size_t ws_size,
                              hipStream_t stream) {
    const float* conc = (const float*)d_in[0];
    const int*   E    = (const int*)d_in[1];
    const int*   S    = (const int*)d_in[2];
    const float* kvec = (const float*)d_in[3];
    float* out = (float*)d_out;

    // ws: VTh fp16 (16 MB) | logcTh fp16 (4 MB) | ecnt | scnt | elist u16 | slist u16
    __half2* VTh     = (__half2*)d_ws;
    __half2* logcTh2 = (__half2*)((char*)d_ws + (size_t)Rr * Bsz * sizeof(__half));
    int*    ecnt     = (int*)((char*)logcTh2 + (size_t)Mm * Bsz * sizeof(__half));
    int*    scnt     = ecnt + Rr;
    ushort_t* elist  = (ushort_t*)(scnt + Mm);
    ushort_t* slist  = elist + Rr * EMAX;
    const size_t need = (size_t)Rr * Bsz * sizeof(__half)
                      + (size_t)Mm * Bsz * sizeof(__half)
                      + (size_t)(Rr + Mm) * sizeof(int)
                      + (size_t)(Rr * EMAX + Mm * SMAX) * sizeof(ushort_t);
    if (ws_size < need) return;

    zero_ecnt<<<32, 256, 0, stream>>>(ecnt);
    prep_kernel<<<2560, 256, 0, stream>>>(conc, E, logcTh2, ecnt, elist);
    rs_kernel<<<4096, 256, 0, stream>>>(logcTh2, kvec, ecnt, elist, S, scnt, slist, VTh);
    assemble_kernel<<<1024, 256, 0, stream>>>(VTh, scnt, slist, out);
}